// Round 8
// baseline (365.129 us; speedup 1.0000x reference)
//
#include <hip/hip_runtime.h>
#include <hip/hip_fp16.h>

#define N_NODES 100000
#define N_EDGES 3200000
#define IN_DIM 128
#define HID 64
#define NUM_GRAPHS 512
#define NUM_CLASSES 10

#define BSHIFT 9
#define BUCKET_W 512
#define NBUCKET ((N_NODES + BUCKET_W - 1) / BUCKET_W)  // 196
#define SRC_BITS 17
#define SRC_MASK ((1 << SRC_BITS) - 1)

typedef _Float16 f16;
typedef f16 f16x8 __attribute__((ext_vector_type(8)));
typedef float f32x4 __attribute__((ext_vector_type(4)));

// ---------------- CSR build (bucketed, no per-edge global atomics) ----------

__global__ __launch_bounds__(256) void bucket_hist_kernel(const int* __restrict__ dst,
                                                          int* __restrict__ bucket_cnt,
                                                          int* __restrict__ blk_hist) {
  __shared__ int h[NBUCKET];
  for (int i = threadIdx.x; i < NBUCKET; i += 256) h[i] = 0;
  __syncthreads();
  const int4* d4 = (const int4*)dst;
  const int nv = N_EDGES / 4 / 256;  // 3125 vectors per block
  int v0 = blockIdx.x * nv, v1 = v0 + nv;
  for (int v = v0 + threadIdx.x; v < v1; v += 256) {
    int4 d = d4[v];
    atomicAdd(&h[d.x >> BSHIFT], 1);
    atomicAdd(&h[d.y >> BSHIFT], 1);
    atomicAdd(&h[d.z >> BSHIFT], 1);
    atomicAdd(&h[d.w >> BSHIFT], 1);
  }
  __syncthreads();
  for (int i = threadIdx.x; i < NBUCKET; i += 256) {
    int c = h[i];
    blk_hist[blockIdx.x * NBUCKET + i] = c;
    if (c) atomicAdd(&bucket_cnt[i], c);
  }
}

__global__ __launch_bounds__(64) void bucket_scan_kernel(const int* __restrict__ bucket_cnt,
                                                         int* __restrict__ bucket_base,
                                                         int* __restrict__ bucket_cursor,
                                                         int* __restrict__ row_ptr) {
  int lane = threadIdx.x;
  int carry = 0;
  for (int base = 0; base < NBUCKET; base += 64) {
    int i = base + lane;
    int v = (i < NBUCKET) ? bucket_cnt[i] : 0;
    int x = v;
#pragma unroll
    for (int off = 1; off < 64; off <<= 1) {
      int t = __shfl_up(x, off);
      if (lane >= off) x += t;
    }
    if (i < NBUCKET) {
      int ex = carry + x - v;
      bucket_base[i] = ex;
      bucket_cursor[i] = ex;
    }
    carry += __shfl(x, 63);
  }
  if (lane == 0) {
    bucket_base[NBUCKET] = carry;
    row_ptr[N_NODES] = carry;  // == N_EDGES
  }
}

__global__ __launch_bounds__(256) void pair_scatter_kernel(const int* __restrict__ src,
                                                           const int* __restrict__ dst,
                                                           int* __restrict__ bucket_cursor,
                                                           const int* __restrict__ blk_hist,
                                                           unsigned* __restrict__ pair_buf) {
  __shared__ int h[NBUCKET];
  for (int i = threadIdx.x; i < NBUCKET; i += 256) {
    int c = blk_hist[blockIdx.x * NBUCKET + i];
    h[i] = c ? atomicAdd(&bucket_cursor[i], c) : 0;
  }
  __syncthreads();
  const int4* d4 = (const int4*)dst;
  const int4* s4 = (const int4*)src;
  const int nv = N_EDGES / 4 / 256;  // 3125
  int v0 = blockIdx.x * nv, v1 = v0 + nv;
  for (int v = v0 + threadIdx.x; v < v1; v += 256) {
    int4 d = d4[v];
    int4 s = s4[v];
    int p0 = atomicAdd(&h[d.x >> BSHIFT], 1);
    pair_buf[p0] = ((unsigned)(d.x & (BUCKET_W - 1)) << SRC_BITS) | (unsigned)s.x;
    int p1 = atomicAdd(&h[d.y >> BSHIFT], 1);
    pair_buf[p1] = ((unsigned)(d.y & (BUCKET_W - 1)) << SRC_BITS) | (unsigned)s.y;
    int p2 = atomicAdd(&h[d.z >> BSHIFT], 1);
    pair_buf[p2] = ((unsigned)(d.z & (BUCKET_W - 1)) << SRC_BITS) | (unsigned)s.z;
    int p3 = atomicAdd(&h[d.w >> BSHIFT], 1);
    pair_buf[p3] = ((unsigned)(d.w & (BUCKET_W - 1)) << SRC_BITS) | (unsigned)s.w;
  }
}

__global__ __launch_bounds__(256) void bucket_fill_kernel(const unsigned* __restrict__ pair_buf,
                                                          const int* __restrict__ bucket_base,
                                                          int* __restrict__ csr_src,
                                                          int* __restrict__ row_ptr,
                                                          float* __restrict__ dinv) {
  int b = blockIdx.x;
  int n0 = b << BSHIFT;
  int nn = min(BUCKET_W, N_NODES - n0);
  int eb0 = bucket_base[b], eb1 = bucket_base[b + 1];
  __shared__ int hist[BUCKET_W];
  __shared__ int wsum[4];
  int tid = threadIdx.x;
  hist[tid] = 0;
  hist[tid + 256] = 0;
  __syncthreads();
  for (int e = eb0 + tid; e < eb1; e += 256)
    atomicAdd(&hist[pair_buf[e] >> SRC_BITS], 1);
  __syncthreads();
  int h0 = hist[2 * tid], h1 = hist[2 * tid + 1];
  int v = h0 + h1;
  int lane = tid & 63, wid = tid >> 6;
  int x = v;
#pragma unroll
  for (int off = 1; off < 64; off <<= 1) {
    int t = __shfl_up(x, off);
    if (lane >= off) x += t;
  }
  if (lane == 63) wsum[wid] = x;
  __syncthreads();
  if (tid == 0) {
    int c = 0;
#pragma unroll
    for (int i = 0; i < 4; ++i) {
      int t = wsum[i];
      wsum[i] = c;
      c += t;
    }
  }
  __syncthreads();
  int base0 = eb0 + x - v + wsum[wid];
  int base1 = base0 + h0;
  if (2 * tid < nn) {
    row_ptr[n0 + 2 * tid] = base0;
    dinv[n0 + 2 * tid] = rsqrtf((float)(h0 + 1));
  }
  if (2 * tid + 1 < nn) {
    row_ptr[n0 + 2 * tid + 1] = base1;
    dinv[n0 + 2 * tid + 1] = rsqrtf((float)(h1 + 1));
  }
  __syncthreads();
  hist[2 * tid] = base0;
  hist[2 * tid + 1] = base1;
  __syncthreads();
  for (int e = eb0 + tid; e < eb1; e += 256) {
    unsigned p = pair_buf[e];
    int pos = atomicAdd(&hist[p >> SRC_BITS], 1);
    csr_src[pos] = (int)(p & SRC_MASK);
  }
}

// ---------------- MFMA GEMM: hp[n][64] = f16((A[n][K]@W[K][64])*dinv[n]) ----
template <int K, bool SRC_F32>
__global__ __launch_bounds__(256) void mfma_gemm_kernel(const void* __restrict__ Asrc,
                                                        const float* __restrict__ W,
                                                        const float* __restrict__ dinv,
                                                        f16* __restrict__ hp, int n) {
  __shared__ f16 Ah[64][K + 8];
  __shared__ f16 Wt[64][K + 8];  // Wt[c][k] = W[k][c]
  int tid = threadIdx.x;
  int row0 = blockIdx.x * 64;
  for (int idx = tid; idx < K * 64; idx += 256) {
    int k = idx >> 6, c = idx & 63;
    Wt[c][k] = (f16)W[idx];
  }
  if (SRC_F32) {
    const float* A = (const float*)Asrc;
    for (int idx = tid * 4; idx < 64 * K; idx += 1024) {
      int r = idx / K, c = idx % K;
      float4 v = make_float4(0.f, 0.f, 0.f, 0.f);
      if (row0 + r < n) v = *(const float4*)&A[(size_t)(row0 + r) * K + c];
      Ah[r][c] = (f16)v.x;
      Ah[r][c + 1] = (f16)v.y;
      Ah[r][c + 2] = (f16)v.z;
      Ah[r][c + 3] = (f16)v.w;
    }
  } else {
    const f16* A = (const f16*)Asrc;
    for (int idx = tid * 8; idx < 64 * K; idx += 2048) {
      int r = idx / K, c = idx % K;
      uint4 z = make_uint4(0u, 0u, 0u, 0u);
      if (row0 + r < n) z = *(const uint4*)&A[(size_t)(row0 + r) * K + c];
      *(uint4*)&Ah[r][c] = z;
    }
  }
  __syncthreads();
  int w = tid >> 6, lane = tid & 63;
  int m0 = 16 * w;
  int arow = m0 + (lane & 15);
  int kbase = (lane >> 4) * 8;
  f32x4 acc[4] = {};
#pragma unroll
  for (int ks = 0; ks < K / 32; ++ks) {
    f16x8 a = *(const f16x8*)&Ah[arow][32 * ks + kbase];
#pragma unroll
    for (int t = 0; t < 4; ++t) {
      f16x8 b = *(const f16x8*)&Wt[16 * t + (lane & 15)][32 * ks + kbase];
      acc[t] = __builtin_amdgcn_mfma_f32_16x16x32_f16(a, b, acc[t], 0, 0, 0);
    }
  }
#pragma unroll
  for (int j = 0; j < 4; ++j) {
    int grow = row0 + m0 + (lane >> 4) * 4 + j;
    if (grow < n) {
      float di = dinv[grow];
#pragma unroll
      for (int t = 0; t < 4; ++t)
        hp[(size_t)grow * 64 + 16 * t + (lane & 15)] = (f16)(acc[t][j] * di);
    }
  }
}

// ---------------- Aggregate (quarter-wave half4 gather, tiered unroll) ------
// 4 edge streams per wave (p = lane>>4), each lane covers dims 4l..4l+3 via
// an 8B (half4) load. 8 loads x 8B in flight per lane at the deepest tier.
#define GATH4(H)                                                       \
  {                                                                    \
    int s_[H];                                                         \
    _Pragma("unroll") for (int i_ = 0; i_ < H; ++i_)                   \
        s_[i_] = csr_src[e + 4 * i_ + p];                              \
    uint2 v_[H];                                                       \
    _Pragma("unroll") for (int i_ = 0; i_ < H; ++i_)                   \
        v_[i_] = hp4[(unsigned)(s_[i_] * 16 + l)];                     \
    _Pragma("unroll") for (int i_ = 0; i_ < H; ++i_) {                 \
      float2 fa = __half22float2(*(const __half2*)&v_[i_].x);          \
      float2 fb = __half22float2(*(const __half2*)&v_[i_].y);          \
      acc.x += fa.x;                                                   \
      acc.y += fa.y;                                                   \
      acc.z += fb.x;                                                   \
      acc.w += fb.y;                                                   \
    }                                                                  \
  }

__global__ __launch_bounds__(256) void aggregate_kernel(
    const __half* __restrict__ hp, const int* __restrict__ row_ptr,
    const int* __restrict__ csr_src, const float* __restrict__ dinv,
    const float* __restrict__ bias, __half* __restrict__ out, int relu) {
  int node = blockIdx.x * 4 + (threadIdx.x >> 6);
  if (node >= N_NODES) return;
  int lane = threadIdx.x & 63;
  int p = lane >> 4;  // edge stream 0..3
  int l = lane & 15;  // dim quad: dims 4l..4l+3
  const uint2* hp4 = (const uint2*)hp;
  int beg = row_ptr[node], end = row_ptr[node + 1];
  float4 acc = make_float4(0.f, 0.f, 0.f, 0.f);
  if (p == 0) {  // self loop
    uint2 u = hp4[(unsigned)(node * 16 + l)];
    float2 fa = __half22float2(*(const __half2*)&u.x);
    float2 fb = __half22float2(*(const __half2*)&u.y);
    acc.x = fa.x;
    acc.y = fa.y;
    acc.z = fb.x;
    acc.w = fb.y;
  }
  int e = beg;
  int rem = end - beg;
  while (rem >= 32) {
    GATH4(8);
    e += 32;
    rem -= 32;
  }
  if (rem >= 16) {
    GATH4(4);
    e += 16;
    rem -= 16;
  }
  if (rem >= 8) {
    GATH4(2);
    e += 8;
    rem -= 8;
  }
  if (rem >= 4) {
    GATH4(1);
    e += 4;
    rem -= 4;
  }
  if (p == 0) {  // 0..3 leftover edges, serial on stream 0
    for (int i = 0; i < rem; ++i) {
      uint2 u = hp4[(unsigned)(csr_src[e + i] * 16 + l)];
      float2 fa = __half22float2(*(const __half2*)&u.x);
      float2 fb = __half22float2(*(const __half2*)&u.y);
      acc.x += fa.x;
      acc.y += fa.y;
      acc.z += fb.x;
      acc.w += fb.y;
    }
  }
  // reduce the 4 parities: lanes l, l+16, l+32, l+48 -> lane l
  acc.x += __shfl_xor(acc.x, 16);
  acc.y += __shfl_xor(acc.y, 16);
  acc.z += __shfl_xor(acc.z, 16);
  acc.w += __shfl_xor(acc.w, 16);
  acc.x += __shfl_xor(acc.x, 32);
  acc.y += __shfl_xor(acc.y, 32);
  acc.z += __shfl_xor(acc.z, 32);
  acc.w += __shfl_xor(acc.w, 32);
  if (p == 0) {
    float di = dinv[node];
    float4 b4 = *(const float4*)&bias[4 * l];
    float rx = acc.x * di + b4.x;
    float ry = acc.y * di + b4.y;
    float rz = acc.z * di + b4.z;
    float rw = acc.w * di + b4.w;
    if (relu) {
      rx = fmaxf(rx, 0.0f);
      ry = fmaxf(ry, 0.0f);
      rz = fmaxf(rz, 0.0f);
      rw = fmaxf(rw, 0.0f);
    }
    uint2 pk;
    *(__half2*)&pk.x = __floats2half2_rn(rx, ry);
    *(__half2*)&pk.y = __floats2half2_rn(rz, rw);
    ((uint2*)out)[(unsigned)(node * 16 + l)] = pk;
  }
}

// ---------------- Global mean pool (batch sorted, fp16 in) ------------------
__global__ __launch_bounds__(256) void pool_kernel(const __half* __restrict__ h,
                                                   const int* __restrict__ batch,
                                                   float* __restrict__ pool,
                                                   int* __restrict__ cnt) {
  int waves = gridDim.x * (blockDim.x >> 6);
  int wave = blockIdx.x * (blockDim.x >> 6) + (threadIdx.x >> 6);
  int lane = threadIdx.x & 63;
  int chunk = (N_NODES + waves - 1) / waves;
  int n0 = wave * chunk;
  int n1 = min(n0 + chunk, N_NODES);
  if (n0 >= n1) return;
  int cur = batch[n0];
  float acc = 0.f;
  int c = 0;
  for (int nn = n0; nn < n1; ++nn) {
    int g = batch[nn];
    if (g != cur) {
      atomicAdd(&pool[(size_t)cur * HID + lane], acc);
      if (lane == 0) atomicAdd(&cnt[cur], c);
      acc = 0.f;
      c = 0;
      cur = g;
    }
    acc += __half2float(h[(size_t)nn * HID + lane]);
    ++c;
  }
  atomicAdd(&pool[(size_t)cur * HID + lane], acc);
  if (lane == 0) atomicAdd(&cnt[cur], c);
}

// ---------------- FC ---------------------------------------------------------
__global__ __launch_bounds__(64) void fc_kernel(const float* __restrict__ pool,
                                                const int* __restrict__ cnt,
                                                const float* __restrict__ Wfc,
                                                const float* __restrict__ bfc,
                                                float* __restrict__ out) {
  int g = blockIdx.x;
  int t = threadIdx.x;
  __shared__ float row[64];
  float inv = 1.0f / fmaxf((float)cnt[g], 1.0f);
  row[t] = pool[(size_t)g * HID + t] * inv;
  __syncthreads();
  if (t < NUM_CLASSES) {
    float acc = bfc[t];
#pragma unroll
    for (int k = 0; k < HID; ++k) acc += row[k] * Wfc[k * NUM_CLASSES + t];
    out[(size_t)g * NUM_CLASSES + t] = acc;
  }
}

// ---------------- launch -----------------------------------------------------
extern "C" void kernel_launch(void* const* d_in, const int* in_sizes, int n_in,
                              void* d_out, int out_size, void* d_ws, size_t ws_size,
                              hipStream_t stream) {
  const float* x = (const float*)d_in[0];
  const int* edge_index = (const int*)d_in[1];
  const int* batch = (const int*)d_in[2];
  const float* W1 = (const float*)d_in[3];
  const float* b1 = (const float*)d_in[4];
  const float* W2 = (const float*)d_in[5];
  const float* b2 = (const float*)d_in[6];
  const float* W3 = (const float*)d_in[7];
  const float* b3 = (const float*)d_in[8];
  const float* Wfc = (const float*)d_in[9];
  const float* bfc = (const float*)d_in[10];
  float* out = (float*)d_out;

  const int* src = edge_index;
  const int* dst = edge_index + N_EDGES;

  // workspace layout
  char* w = (char*)d_ws;
  __half* h16 = (__half*)w;                        // N*64 f16 (aggregate out / GEMM A)
  __half* hp = h16 + (size_t)N_NODES * HID;        // N*64 f16 (GEMM out, gather buf)
  float* dinv = (float*)(hp + (size_t)N_NODES * HID);  // N
  int* row_ptr = (int*)(dinv + N_NODES);           // N+1
  int* csr_src = row_ptr + (N_NODES + 1);          // E
  int* bucket_cnt = csr_src + N_EDGES;             // NBUCKET
  int* bucket_base = bucket_cnt + NBUCKET;         // NBUCKET+1
  int* bucket_cursor = bucket_base + NBUCKET + 1;  // NBUCKET
  float* pool = (float*)(bucket_cursor + NBUCKET); // 512*64
  int* cnt = (int*)(pool + NUM_GRAPHS * HID);      // 512
  int* blk_hist = cnt + NUM_GRAPHS;                // 256*NBUCKET
  unsigned* pair_buf = (unsigned*)h16;  // alias: dead before aggregate1 writes h16

  hipMemsetAsync(bucket_cnt, 0, NBUCKET * sizeof(int), stream);
  hipMemsetAsync(pool, 0, NUM_GRAPHS * HID * sizeof(float), stream);
  hipMemsetAsync(cnt, 0, NUM_GRAPHS * sizeof(int), stream);

  // CSR build
  bucket_hist_kernel<<<256, 256, 0, stream>>>(dst, bucket_cnt, blk_hist);
  bucket_scan_kernel<<<1, 64, 0, stream>>>(bucket_cnt, bucket_base, bucket_cursor,
                                           row_ptr);
  pair_scatter_kernel<<<256, 256, 0, stream>>>(src, dst, bucket_cursor, blk_hist,
                                               pair_buf);
  bucket_fill_kernel<<<NBUCKET, 256, 0, stream>>>(pair_buf, bucket_base, csr_src,
                                                  row_ptr, dinv);

  const int ggrid = (N_NODES + 63) / 64;
  const int agrid = (N_NODES + 3) / 4;

  // layer 1
  mfma_gemm_kernel<IN_DIM, true><<<ggrid, 256, 0, stream>>>(x, W1, dinv, (f16*)hp,
                                                            N_NODES);
  aggregate_kernel<<<agrid, 256, 0, stream>>>(hp, row_ptr, csr_src, dinv, b1, h16, 1);
  // layer 2
  mfma_gemm_kernel<HID, false><<<ggrid, 256, 0, stream>>>(h16, W2, dinv, (f16*)hp,
                                                          N_NODES);
  aggregate_kernel<<<agrid, 256, 0, stream>>>(hp, row_ptr, csr_src, dinv, b2, h16, 1);
  // layer 3
  mfma_gemm_kernel<HID, false><<<ggrid, 256, 0, stream>>>(h16, W3, dinv, (f16*)hp,
                                                          N_NODES);
  aggregate_kernel<<<agrid, 256, 0, stream>>>(hp, row_ptr, csr_src, dinv, b3, h16, 0);

  // pool + fc
  pool_kernel<<<512, 256, 0, stream>>>(h16, batch, pool, cnt);
  fc_kernel<<<NUM_GRAPHS, 64, 0, stream>>>(pool, cnt, Wfc, bfc, out);
}

// Round 9
// 326.287 us; speedup vs baseline: 1.1190x; 1.1190x over previous
//
#include <hip/hip_runtime.h>
#include <hip/hip_fp16.h>

#define N_NODES 100000
#define N_EDGES 3200000
#define IN_DIM 128
#define HID 64
#define NUM_GRAPHS 512
#define NUM_CLASSES 10

#define BSHIFT 9
#define BUCKET_W 512
#define NBUCKET ((N_NODES + BUCKET_W - 1) / BUCKET_W)  // 196
#define SRC_BITS 17
#define SRC_MASK ((1 << SRC_BITS) - 1)

typedef _Float16 f16;
typedef f16 f16x8 __attribute__((ext_vector_type(8)));
typedef float f32x4 __attribute__((ext_vector_type(4)));

// ---------------- CSR build (bucketed, no per-edge global atomics) ----------

__global__ __launch_bounds__(256) void bucket_hist_kernel(const int* __restrict__ dst,
                                                          int* __restrict__ bucket_cnt,
                                                          int* __restrict__ blk_hist) {
  __shared__ int h[NBUCKET];
  for (int i = threadIdx.x; i < NBUCKET; i += 256) h[i] = 0;
  __syncthreads();
  const int4* d4 = (const int4*)dst;
  const int nv = N_EDGES / 4 / 256;  // 3125 vectors per block
  int v0 = blockIdx.x * nv, v1 = v0 + nv;
  for (int v = v0 + threadIdx.x; v < v1; v += 256) {
    int4 d = d4[v];
    atomicAdd(&h[d.x >> BSHIFT], 1);
    atomicAdd(&h[d.y >> BSHIFT], 1);
    atomicAdd(&h[d.z >> BSHIFT], 1);
    atomicAdd(&h[d.w >> BSHIFT], 1);
  }
  __syncthreads();
  for (int i = threadIdx.x; i < NBUCKET; i += 256) {
    int c = h[i];
    blk_hist[blockIdx.x * NBUCKET + i] = c;
    if (c) atomicAdd(&bucket_cnt[i], c);
  }
}

__global__ __launch_bounds__(64) void bucket_scan_kernel(const int* __restrict__ bucket_cnt,
                                                         int* __restrict__ bucket_base,
                                                         int* __restrict__ bucket_cursor,
                                                         int* __restrict__ row_ptr) {
  int lane = threadIdx.x;
  int carry = 0;
  for (int base = 0; base < NBUCKET; base += 64) {
    int i = base + lane;
    int v = (i < NBUCKET) ? bucket_cnt[i] : 0;
    int x = v;
#pragma unroll
    for (int off = 1; off < 64; off <<= 1) {
      int t = __shfl_up(x, off);
      if (lane >= off) x += t;
    }
    if (i < NBUCKET) {
      int ex = carry + x - v;
      bucket_base[i] = ex;
      bucket_cursor[i] = ex;
    }
    carry += __shfl(x, 63);
  }
  if (lane == 0) {
    bucket_base[NBUCKET] = carry;
    row_ptr[N_NODES] = carry;  // == N_EDGES
  }
}

__global__ __launch_bounds__(256) void pair_scatter_kernel(const int* __restrict__ src,
                                                           const int* __restrict__ dst,
                                                           int* __restrict__ bucket_cursor,
                                                           const int* __restrict__ blk_hist,
                                                           unsigned* __restrict__ pair_buf) {
  __shared__ int h[NBUCKET];
  for (int i = threadIdx.x; i < NBUCKET; i += 256) {
    int c = blk_hist[blockIdx.x * NBUCKET + i];
    h[i] = c ? atomicAdd(&bucket_cursor[i], c) : 0;
  }
  __syncthreads();
  const int4* d4 = (const int4*)dst;
  const int4* s4 = (const int4*)src;
  const int nv = N_EDGES / 4 / 256;  // 3125
  int v0 = blockIdx.x * nv, v1 = v0 + nv;
  for (int v = v0 + threadIdx.x; v < v1; v += 256) {
    int4 d = d4[v];
    int4 s = s4[v];
    int p0 = atomicAdd(&h[d.x >> BSHIFT], 1);
    pair_buf[p0] = ((unsigned)(d.x & (BUCKET_W - 1)) << SRC_BITS) | (unsigned)s.x;
    int p1 = atomicAdd(&h[d.y >> BSHIFT], 1);
    pair_buf[p1] = ((unsigned)(d.y & (BUCKET_W - 1)) << SRC_BITS) | (unsigned)s.y;
    int p2 = atomicAdd(&h[d.z >> BSHIFT], 1);
    pair_buf[p2] = ((unsigned)(d.z & (BUCKET_W - 1)) << SRC_BITS) | (unsigned)s.z;
    int p3 = atomicAdd(&h[d.w >> BSHIFT], 1);
    pair_buf[p3] = ((unsigned)(d.w & (BUCKET_W - 1)) << SRC_BITS) | (unsigned)s.w;
  }
}

__global__ __launch_bounds__(256) void bucket_fill_kernel(const unsigned* __restrict__ pair_buf,
                                                          const int* __restrict__ bucket_base,
                                                          int* __restrict__ csr_src,
                                                          int* __restrict__ row_ptr,
                                                          float* __restrict__ dinv) {
  int b = blockIdx.x;
  int n0 = b << BSHIFT;
  int nn = min(BUCKET_W, N_NODES - n0);
  int eb0 = bucket_base[b], eb1 = bucket_base[b + 1];
  __shared__ int hist[BUCKET_W];
  __shared__ int wsum[4];
  int tid = threadIdx.x;
  hist[tid] = 0;
  hist[tid + 256] = 0;
  __syncthreads();
  for (int e = eb0 + tid; e < eb1; e += 256)
    atomicAdd(&hist[pair_buf[e] >> SRC_BITS], 1);
  __syncthreads();
  int h0 = hist[2 * tid], h1 = hist[2 * tid + 1];
  int v = h0 + h1;
  int lane = tid & 63, wid = tid >> 6;
  int x = v;
#pragma unroll
  for (int off = 1; off < 64; off <<= 1) {
    int t = __shfl_up(x, off);
    if (lane >= off) x += t;
  }
  if (lane == 63) wsum[wid] = x;
  __syncthreads();
  if (tid == 0) {
    int c = 0;
#pragma unroll
    for (int i = 0; i < 4; ++i) {
      int t = wsum[i];
      wsum[i] = c;
      c += t;
    }
  }
  __syncthreads();
  int base0 = eb0 + x - v + wsum[wid];
  int base1 = base0 + h0;
  if (2 * tid < nn) {
    row_ptr[n0 + 2 * tid] = base0;
    dinv[n0 + 2 * tid] = rsqrtf((float)(h0 + 1));
  }
  if (2 * tid + 1 < nn) {
    row_ptr[n0 + 2 * tid + 1] = base1;
    dinv[n0 + 2 * tid + 1] = rsqrtf((float)(h1 + 1));
  }
  __syncthreads();
  hist[2 * tid] = base0;
  hist[2 * tid + 1] = base1;
  __syncthreads();
  for (int e = eb0 + tid; e < eb1; e += 256) {
    unsigned p = pair_buf[e];
    int pos = atomicAdd(&hist[p >> SRC_BITS], 1);
    csr_src[pos] = (int)(p & SRC_MASK);
  }
}

// ---------------- MFMA GEMM: hp[n][64] = f16((A[n][K]@W[K][64])*dinv[n]) ----
template <int K, bool SRC_F32>
__global__ __launch_bounds__(256) void mfma_gemm_kernel(const void* __restrict__ Asrc,
                                                        const float* __restrict__ W,
                                                        const float* __restrict__ dinv,
                                                        f16* __restrict__ hp, int n) {
  __shared__ f16 Ah[64][K + 8];
  __shared__ f16 Wt[64][K + 8];  // Wt[c][k] = W[k][c]
  int tid = threadIdx.x;
  int row0 = blockIdx.x * 64;
  for (int idx = tid; idx < K * 64; idx += 256) {
    int k = idx >> 6, c = idx & 63;
    Wt[c][k] = (f16)W[idx];
  }
  if (SRC_F32) {
    const float* A = (const float*)Asrc;
    for (int idx = tid * 4; idx < 64 * K; idx += 1024) {
      int r = idx / K, c = idx % K;
      float4 v = make_float4(0.f, 0.f, 0.f, 0.f);
      if (row0 + r < n) v = *(const float4*)&A[(size_t)(row0 + r) * K + c];
      Ah[r][c] = (f16)v.x;
      Ah[r][c + 1] = (f16)v.y;
      Ah[r][c + 2] = (f16)v.z;
      Ah[r][c + 3] = (f16)v.w;
    }
  } else {
    const f16* A = (const f16*)Asrc;
    for (int idx = tid * 8; idx < 64 * K; idx += 2048) {
      int r = idx / K, c = idx % K;
      uint4 z = make_uint4(0u, 0u, 0u, 0u);
      if (row0 + r < n) z = *(const uint4*)&A[(size_t)(row0 + r) * K + c];
      *(uint4*)&Ah[r][c] = z;
    }
  }
  __syncthreads();
  int w = tid >> 6, lane = tid & 63;
  int m0 = 16 * w;
  int arow = m0 + (lane & 15);
  int kbase = (lane >> 4) * 8;
  f32x4 acc[4] = {};
#pragma unroll
  for (int ks = 0; ks < K / 32; ++ks) {
    f16x8 a = *(const f16x8*)&Ah[arow][32 * ks + kbase];
#pragma unroll
    for (int t = 0; t < 4; ++t) {
      f16x8 b = *(const f16x8*)&Wt[16 * t + (lane & 15)][32 * ks + kbase];
      acc[t] = __builtin_amdgcn_mfma_f32_16x16x32_f16(a, b, acc[t], 0, 0, 0);
    }
  }
#pragma unroll
  for (int j = 0; j < 4; ++j) {
    int grow = row0 + m0 + (lane >> 4) * 4 + j;
    if (grow < n) {
      float di = dinv[grow];
#pragma unroll
      for (int t = 0; t < 4; ++t)
        hp[(size_t)grow * 64 + 16 * t + (lane & 15)] = (f16)(acc[t][j] * di);
    }
  }
}

// ---------------- Aggregate: 2 nodes per wave, half-wave per node -----------
// Each half-wave (32 lanes) owns one node: lane covers dims {2l,2l+1} via
// half2. Tiers {16,8,4,2,1} edges -> up to 16 outstanding gathers per
// half-wave (32 per wave). No cross-lane reduction needed.
#define GATH2(H)                                                     \
  {                                                                  \
    int s_[H];                                                       \
    _Pragma("unroll") for (int i_ = 0; i_ < H; ++i_)                 \
        s_[i_] = csr_src[e + i_];                                    \
    float2 v_[H];                                                    \
    _Pragma("unroll") for (int i_ = 0; i_ < H; ++i_)                 \
        v_[i_] = __half22float2(hp2[(unsigned)(s_[i_] * 32 + l)]);   \
    _Pragma("unroll") for (int i_ = 0; i_ < H; ++i_) {               \
      acc.x += v_[i_].x;                                             \
      acc.y += v_[i_].y;                                             \
    }                                                                \
  }

__global__ __launch_bounds__(256) void aggregate_kernel(
    const __half* __restrict__ hp, const int* __restrict__ row_ptr,
    const int* __restrict__ csr_src, const float* __restrict__ dinv,
    const float* __restrict__ bias, __half* __restrict__ out, int relu) {
  int node = blockIdx.x * 8 + (threadIdx.x >> 5);
  if (node >= N_NODES) return;
  int l = threadIdx.x & 31;  // dim-pair index
  const __half2* hp2 = (const __half2*)hp;
  int beg = row_ptr[node], end = row_ptr[node + 1];
  // self loop
  float2 acc = __half22float2(hp2[(unsigned)(node * 32 + l)]);
  int e = beg;
  int rem = end - beg;
  while (rem >= 16) {
    GATH2(16);
    e += 16;
    rem -= 16;
  }
  if (rem >= 8) {
    GATH2(8);
    e += 8;
    rem -= 8;
  }
  if (rem >= 4) {
    GATH2(4);
    e += 4;
    rem -= 4;
  }
  if (rem >= 2) {
    GATH2(2);
    e += 2;
    rem -= 2;
  }
  if (rem) {
    GATH2(1);
  }
  float di = dinv[node];
  float2 b = *(const float2*)&bias[2 * l];
  float rx = acc.x * di + b.x;
  float ry = acc.y * di + b.y;
  if (relu) {
    rx = fmaxf(rx, 0.0f);
    ry = fmaxf(ry, 0.0f);
  }
  ((__half2*)out)[(unsigned)(node * 32 + l)] = __floats2half2_rn(rx, ry);
}

// ---------------- Global mean pool (batch sorted, fp16 in) ------------------
__global__ __launch_bounds__(256) void pool_kernel(const __half* __restrict__ h,
                                                   const int* __restrict__ batch,
                                                   float* __restrict__ pool,
                                                   int* __restrict__ cnt) {
  int waves = gridDim.x * (blockDim.x >> 6);
  int wave = blockIdx.x * (blockDim.x >> 6) + (threadIdx.x >> 6);
  int lane = threadIdx.x & 63;
  int chunk = (N_NODES + waves - 1) / waves;
  int n0 = wave * chunk;
  int n1 = min(n0 + chunk, N_NODES);
  if (n0 >= n1) return;
  int cur = batch[n0];
  float acc = 0.f;
  int c = 0;
  for (int nn = n0; nn < n1; ++nn) {
    int g = batch[nn];
    if (g != cur) {
      atomicAdd(&pool[(size_t)cur * HID + lane], acc);
      if (lane == 0) atomicAdd(&cnt[cur], c);
      acc = 0.f;
      c = 0;
      cur = g;
    }
    acc += __half2float(h[(size_t)nn * HID + lane]);
    ++c;
  }
  atomicAdd(&pool[(size_t)cur * HID + lane], acc);
  if (lane == 0) atomicAdd(&cnt[cur], c);
}

// ---------------- FC ---------------------------------------------------------
__global__ __launch_bounds__(64) void fc_kernel(const float* __restrict__ pool,
                                                const int* __restrict__ cnt,
                                                const float* __restrict__ Wfc,
                                                const float* __restrict__ bfc,
                                                float* __restrict__ out) {
  int g = blockIdx.x;
  int t = threadIdx.x;
  __shared__ float row[64];
  float inv = 1.0f / fmaxf((float)cnt[g], 1.0f);
  row[t] = pool[(size_t)g * HID + t] * inv;
  __syncthreads();
  if (t < NUM_CLASSES) {
    float acc = bfc[t];
#pragma unroll
    for (int k = 0; k < HID; ++k) acc += row[k] * Wfc[k * NUM_CLASSES + t];
    out[(size_t)g * NUM_CLASSES + t] = acc;
  }
}

// ---------------- launch -----------------------------------------------------
extern "C" void kernel_launch(void* const* d_in, const int* in_sizes, int n_in,
                              void* d_out, int out_size, void* d_ws, size_t ws_size,
                              hipStream_t stream) {
  const float* x = (const float*)d_in[0];
  const int* edge_index = (const int*)d_in[1];
  const int* batch = (const int*)d_in[2];
  const float* W1 = (const float*)d_in[3];
  const float* b1 = (const float*)d_in[4];
  const float* W2 = (const float*)d_in[5];
  const float* b2 = (const float*)d_in[6];
  const float* W3 = (const float*)d_in[7];
  const float* b3 = (const float*)d_in[8];
  const float* Wfc = (const float*)d_in[9];
  const float* bfc = (const float*)d_in[10];
  float* out = (float*)d_out;

  const int* src = edge_index;
  const int* dst = edge_index + N_EDGES;

  // workspace layout
  char* w = (char*)d_ws;
  __half* h16 = (__half*)w;                        // N*64 f16 (aggregate out / GEMM A)
  __half* hp = h16 + (size_t)N_NODES * HID;        // N*64 f16 (GEMM out, gather buf)
  float* dinv = (float*)(hp + (size_t)N_NODES * HID);  // N
  int* row_ptr = (int*)(dinv + N_NODES);           // N+1
  int* csr_src = row_ptr + (N_NODES + 1);          // E
  int* bucket_cnt = csr_src + N_EDGES;             // NBUCKET
  int* bucket_base = bucket_cnt + NBUCKET;         // NBUCKET+1
  int* bucket_cursor = bucket_base + NBUCKET + 1;  // NBUCKET
  float* pool = (float*)(bucket_cursor + NBUCKET); // 512*64
  int* cnt = (int*)(pool + NUM_GRAPHS * HID);      // 512
  int* blk_hist = cnt + NUM_GRAPHS;                // 256*NBUCKET
  unsigned* pair_buf = (unsigned*)h16;  // alias: dead before aggregate1 writes h16

  hipMemsetAsync(bucket_cnt, 0, NBUCKET * sizeof(int), stream);
  hipMemsetAsync(pool, 0, NUM_GRAPHS * HID * sizeof(float), stream);
  hipMemsetAsync(cnt, 0, NUM_GRAPHS * sizeof(int), stream);

  // CSR build
  bucket_hist_kernel<<<256, 256, 0, stream>>>(dst, bucket_cnt, blk_hist);
  bucket_scan_kernel<<<1, 64, 0, stream>>>(bucket_cnt, bucket_base, bucket_cursor,
                                           row_ptr);
  pair_scatter_kernel<<<256, 256, 0, stream>>>(src, dst, bucket_cursor, blk_hist,
                                               pair_buf);
  bucket_fill_kernel<<<NBUCKET, 256, 0, stream>>>(pair_buf, bucket_base, csr_src,
                                                  row_ptr, dinv);

  const int ggrid = (N_NODES + 63) / 64;
  const int agrid = (N_NODES + 7) / 8;

  // layer 1
  mfma_gemm_kernel<IN_DIM, true><<<ggrid, 256, 0, stream>>>(x, W1, dinv, (f16*)hp,
                                                            N_NODES);
  aggregate_kernel<<<agrid, 256, 0, stream>>>(hp, row_ptr, csr_src, dinv, b1, h16, 1);
  // layer 2
  mfma_gemm_kernel<HID, false><<<ggrid, 256, 0, stream>>>(h16, W2, dinv, (f16*)hp,
                                                          N_NODES);
  aggregate_kernel<<<agrid, 256, 0, stream>>>(hp, row_ptr, csr_src, dinv, b2, h16, 1);
  // layer 3
  mfma_gemm_kernel<HID, false><<<ggrid, 256, 0, stream>>>(h16, W3, dinv, (f16*)hp,
                                                          N_NODES);
  aggregate_kernel<<<agrid, 256, 0, stream>>>(hp, row_ptr, csr_src, dinv, b3, h16, 0);

  // pool + fc
  pool_kernel<<<512, 256, 0, stream>>>(h16, batch, pool, cnt);
  fc_kernel<<<NUM_GRAPHS, 64, 0, stream>>>(pool, cnt, Wfc, bfc, out);
}

// Round 10
// 310.289 us; speedup vs baseline: 1.1767x; 1.0516x over previous
//
#include <hip/hip_runtime.h>
#include <hip/hip_fp16.h>

#define N_NODES 100000
#define N_EDGES 3200000
#define IN_DIM 128
#define HID 64
#define NUM_GRAPHS 512
#define NUM_CLASSES 10

#define BSHIFT 9
#define BUCKET_W 512
#define NBUCKET ((N_NODES + BUCKET_W - 1) / BUCKET_W)  // 196
#define SRC_BITS 17
#define SRC_MASK ((1 << SRC_BITS) - 1)
#define NHBLK 256  // blocks in hist/scatter

typedef _Float16 f16;
typedef f16 f16x8 __attribute__((ext_vector_type(8)));
typedef float f32x4 __attribute__((ext_vector_type(4)));

// ---------------- CSR build (bucketed, no per-edge global atomics) ----------

// 256 blocks, int4 edge reads, LDS hist; persists per-block hist (no global
// bucket_cnt atomics -- scan sums blk_hist columns itself).
__global__ __launch_bounds__(256) void bucket_hist_kernel(const int* __restrict__ dst,
                                                          int* __restrict__ blk_hist) {
  __shared__ int h[NBUCKET];
  for (int i = threadIdx.x; i < NBUCKET; i += 256) h[i] = 0;
  __syncthreads();
  const int4* d4 = (const int4*)dst;
  const int nv = N_EDGES / 4 / NHBLK;  // 3125 vectors per block
  int v0 = blockIdx.x * nv, v1 = v0 + nv;
  for (int v = v0 + threadIdx.x; v < v1; v += 256) {
    int4 d = d4[v];
    atomicAdd(&h[d.x >> BSHIFT], 1);
    atomicAdd(&h[d.y >> BSHIFT], 1);
    atomicAdd(&h[d.z >> BSHIFT], 1);
    atomicAdd(&h[d.w >> BSHIFT], 1);
  }
  __syncthreads();
  for (int i = threadIdx.x; i < NBUCKET; i += 256)
    blk_hist[blockIdx.x * NBUCKET + i] = h[i];
}

// single block: bucket_cnt[i] = sum_b blk_hist[b][i]; exclusive scan -> bases.
__global__ __launch_bounds__(256) void bucket_scan_kernel(const int* __restrict__ blk_hist,
                                                          int* __restrict__ bucket_base,
                                                          int* __restrict__ bucket_cursor,
                                                          int* __restrict__ row_ptr) {
  __shared__ int cnt[NBUCKET];
  int t = threadIdx.x;
  if (t < NBUCKET) {
    int s = 0;
    for (int b = 0; b < NHBLK; ++b) s += blk_hist[b * NBUCKET + t];
    cnt[t] = s;
  }
  __syncthreads();
  if (t < 64) {
    int carry = 0;
    for (int base = 0; base < NBUCKET; base += 64) {
      int i = base + t;
      int v = (i < NBUCKET) ? cnt[i] : 0;
      int x = v;
#pragma unroll
      for (int off = 1; off < 64; off <<= 1) {
        int tt = __shfl_up(x, off);
        if (t >= off) x += tt;
      }
      if (i < NBUCKET) {
        int ex = carry + x - v;
        bucket_base[i] = ex;
        bucket_cursor[i] = ex;
      }
      carry += __shfl(x, 63);
    }
    if (t == 0) {
      bucket_base[NBUCKET] = carry;
      row_ptr[N_NODES] = carry;  // == N_EDGES
    }
  }
}

// pair = (dst&511)<<17 | src. Uses persisted blk_hist (no re-histogram pass).
__global__ __launch_bounds__(256) void pair_scatter_kernel(const int* __restrict__ src,
                                                           const int* __restrict__ dst,
                                                           int* __restrict__ bucket_cursor,
                                                           const int* __restrict__ blk_hist,
                                                           unsigned* __restrict__ pair_buf) {
  __shared__ int h[NBUCKET];
  for (int i = threadIdx.x; i < NBUCKET; i += 256) {
    int c = blk_hist[blockIdx.x * NBUCKET + i];
    h[i] = c ? atomicAdd(&bucket_cursor[i], c) : 0;
  }
  __syncthreads();
  const int4* d4 = (const int4*)dst;
  const int4* s4 = (const int4*)src;
  const int nv = N_EDGES / 4 / NHBLK;  // 3125
  int v0 = blockIdx.x * nv, v1 = v0 + nv;
  for (int v = v0 + threadIdx.x; v < v1; v += 256) {
    int4 d = d4[v];
    int4 s = s4[v];
    int p0 = atomicAdd(&h[d.x >> BSHIFT], 1);
    pair_buf[p0] = ((unsigned)(d.x & (BUCKET_W - 1)) << SRC_BITS) | (unsigned)s.x;
    int p1 = atomicAdd(&h[d.y >> BSHIFT], 1);
    pair_buf[p1] = ((unsigned)(d.y & (BUCKET_W - 1)) << SRC_BITS) | (unsigned)s.y;
    int p2 = atomicAdd(&h[d.z >> BSHIFT], 1);
    pair_buf[p2] = ((unsigned)(d.z & (BUCKET_W - 1)) << SRC_BITS) | (unsigned)s.z;
    int p3 = atomicAdd(&h[d.w >> BSHIFT], 1);
    pair_buf[p3] = ((unsigned)(d.w & (BUCKET_W - 1)) << SRC_BITS) | (unsigned)s.w;
  }
}

__global__ __launch_bounds__(256) void bucket_fill_kernel(const unsigned* __restrict__ pair_buf,
                                                          const int* __restrict__ bucket_base,
                                                          int* __restrict__ csr_src,
                                                          int* __restrict__ row_ptr,
                                                          float* __restrict__ dinv) {
  int b = blockIdx.x;
  int n0 = b << BSHIFT;
  int nn = min(BUCKET_W, N_NODES - n0);
  int eb0 = bucket_base[b], eb1 = bucket_base[b + 1];
  __shared__ int hist[BUCKET_W];
  __shared__ int wsum[4];
  int tid = threadIdx.x;
  hist[tid] = 0;
  hist[tid + 256] = 0;
  __syncthreads();
  for (int e = eb0 + tid; e < eb1; e += 256)
    atomicAdd(&hist[pair_buf[e] >> SRC_BITS], 1);
  __syncthreads();
  int h0 = hist[2 * tid], h1 = hist[2 * tid + 1];
  int v = h0 + h1;
  int lane = tid & 63, wid = tid >> 6;
  int x = v;
#pragma unroll
  for (int off = 1; off < 64; off <<= 1) {
    int t = __shfl_up(x, off);
    if (lane >= off) x += t;
  }
  if (lane == 63) wsum[wid] = x;
  __syncthreads();
  if (tid == 0) {
    int c = 0;
#pragma unroll
    for (int i = 0; i < 4; ++i) {
      int t = wsum[i];
      wsum[i] = c;
      c += t;
    }
  }
  __syncthreads();
  int base0 = eb0 + x - v + wsum[wid];
  int base1 = base0 + h0;
  if (2 * tid < nn) {
    row_ptr[n0 + 2 * tid] = base0;
    dinv[n0 + 2 * tid] = rsqrtf((float)(h0 + 1));
  }
  if (2 * tid + 1 < nn) {
    row_ptr[n0 + 2 * tid + 1] = base1;
    dinv[n0 + 2 * tid + 1] = rsqrtf((float)(h1 + 1));
  }
  __syncthreads();
  hist[2 * tid] = base0;
  hist[2 * tid + 1] = base1;
  __syncthreads();
  for (int e = eb0 + tid; e < eb1; e += 256) {
    unsigned p = pair_buf[e];
    int pos = atomicAdd(&hist[p >> SRC_BITS], 1);
    csr_src[pos] = (int)(p & SRC_MASK);
  }
}

// ---------------- MFMA GEMM: hp[n][64] = f16((A[n][K]@W[K][64])*dinv[n]) ----
// 128-row block tile, 4 waves; wave w -> rows [32w, 32w+32) as two 16-row
// m-tiles; 4 col-tiles of 16. mfma_f32_16x16x32_f16.
template <int K, bool SRC_F32>
__global__ __launch_bounds__(256) void mfma_gemm_kernel(const void* __restrict__ Asrc,
                                                        const float* __restrict__ W,
                                                        const float* __restrict__ dinv,
                                                        f16* __restrict__ hp, int n) {
  __shared__ f16 Ah[128][K + 8];
  __shared__ f16 Wt[64][K + 8];  // Wt[c][k] = W[k][c]
  int tid = threadIdx.x;
  int row0 = blockIdx.x * 128;
  for (int idx = tid; idx < K * 64; idx += 256) {
    int k = idx >> 6, c = idx & 63;
    Wt[c][k] = (f16)W[idx];
  }
  if (SRC_F32) {
    const float* A = (const float*)Asrc;
    for (int idx = tid * 4; idx < 128 * K; idx += 1024) {
      int r = idx / K, c = idx % K;
      float4 v = make_float4(0.f, 0.f, 0.f, 0.f);
      if (row0 + r < n) v = *(const float4*)&A[(size_t)(row0 + r) * K + c];
      Ah[r][c] = (f16)v.x;
      Ah[r][c + 1] = (f16)v.y;
      Ah[r][c + 2] = (f16)v.z;
      Ah[r][c + 3] = (f16)v.w;
    }
  } else {
    const f16* A = (const f16*)Asrc;
    for (int idx = tid * 8; idx < 128 * K; idx += 2048) {
      int r = idx / K, c = idx % K;
      uint4 z = make_uint4(0u, 0u, 0u, 0u);
      if (row0 + r < n) z = *(const uint4*)&A[(size_t)(row0 + r) * K + c];
      *(uint4*)&Ah[r][c] = z;
    }
  }
  __syncthreads();
  int w = tid >> 6, lane = tid & 63;
  int m0 = 32 * w;
  int kbase = (lane >> 4) * 8;
  int la = lane & 15;
  f32x4 acc[2][4] = {};
#pragma unroll
  for (int ks = 0; ks < K / 32; ++ks) {
    f16x8 a0 = *(const f16x8*)&Ah[m0 + la][32 * ks + kbase];
    f16x8 a1 = *(const f16x8*)&Ah[m0 + 16 + la][32 * ks + kbase];
#pragma unroll
    for (int t = 0; t < 4; ++t) {
      f16x8 b = *(const f16x8*)&Wt[16 * t + la][32 * ks + kbase];
      acc[0][t] = __builtin_amdgcn_mfma_f32_16x16x32_f16(a0, b, acc[0][t], 0, 0, 0);
      acc[1][t] = __builtin_amdgcn_mfma_f32_16x16x32_f16(a1, b, acc[1][t], 0, 0, 0);
    }
  }
#pragma unroll
  for (int mt = 0; mt < 2; ++mt) {
#pragma unroll
    for (int j = 0; j < 4; ++j) {
      int grow = row0 + m0 + 16 * mt + (lane >> 4) * 4 + j;
      if (grow < n) {
        float di = dinv[grow];
#pragma unroll
        for (int t = 0; t < 4; ++t)
          hp[(size_t)grow * 64 + 16 * t + la] = (f16)(acc[mt][t][j] * di);
      }
    }
  }
}

// ---------------- Aggregate: 2 nodes per wave, half-wave per node -----------
#define GATH2(H)                                                     \
  {                                                                  \
    int s_[H];                                                       \
    _Pragma("unroll") for (int i_ = 0; i_ < H; ++i_)                 \
        s_[i_] = csr_src[e + i_];                                    \
    float2 v_[H];                                                    \
    _Pragma("unroll") for (int i_ = 0; i_ < H; ++i_)                 \
        v_[i_] = __half22float2(hp2[(unsigned)(s_[i_] * 32 + l)]);   \
    _Pragma("unroll") for (int i_ = 0; i_ < H; ++i_) {               \
      acc.x += v_[i_].x;                                             \
      acc.y += v_[i_].y;                                             \
    }                                                                \
  }

__global__ __launch_bounds__(256) void aggregate_kernel(
    const __half* __restrict__ hp, const int* __restrict__ row_ptr,
    const int* __restrict__ csr_src, const float* __restrict__ dinv,
    const float* __restrict__ bias, __half* __restrict__ out, int relu) {
  int node = blockIdx.x * 8 + (threadIdx.x >> 5);
  if (node >= N_NODES) return;
  int l = threadIdx.x & 31;  // dim-pair index
  const __half2* hp2 = (const __half2*)hp;
  int beg = row_ptr[node], end = row_ptr[node + 1];
  float2 acc = __half22float2(hp2[(unsigned)(node * 32 + l)]);  // self loop
  int e = beg;
  int rem = end - beg;
  while (rem >= 16) {
    GATH2(16);
    e += 16;
    rem -= 16;
  }
  if (rem >= 8) {
    GATH2(8);
    e += 8;
    rem -= 8;
  }
  if (rem >= 4) {
    GATH2(4);
    e += 4;
    rem -= 4;
  }
  if (rem >= 2) {
    GATH2(2);
    e += 2;
    rem -= 2;
  }
  if (rem) {
    GATH2(1);
  }
  float di = dinv[node];
  float2 b = *(const float2*)&bias[2 * l];
  float rx = acc.x * di + b.x;
  float ry = acc.y * di + b.y;
  if (relu) {
    rx = fmaxf(rx, 0.0f);
    ry = fmaxf(ry, 0.0f);
  }
  ((__half2*)out)[(unsigned)(node * 32 + l)] = __floats2half2_rn(rx, ry);
}

// ---------------- Fused mean-pool + FC (wave per graph, no atomics) ---------
// batch is sorted: binary-search the node range of graph g, lane k sums dim k,
// then 10 butterfly reductions produce out[g][0..9]. No pool buffer/memsets.
__global__ __launch_bounds__(256) void pool_fc_kernel(const __half* __restrict__ h,
                                                      const int* __restrict__ batch,
                                                      const float* __restrict__ Wfc,
                                                      const float* __restrict__ bfc,
                                                      float* __restrict__ out) {
  int g = blockIdx.x * 4 + (threadIdx.x >> 6);
  if (g >= NUM_GRAPHS) return;
  int lane = threadIdx.x & 63;
  int lo = 0, hi = N_NODES;
  while (lo < hi) {
    int m = (lo + hi) >> 1;
    if (batch[m] < g) lo = m + 1; else hi = m;
  }
  int n0 = lo;
  hi = N_NODES;
  while (lo < hi) {
    int m = (lo + hi) >> 1;
    if (batch[m] < g + 1) lo = m + 1; else hi = m;
  }
  int n1 = lo;
  float acc = 0.f, acc2 = 0.f;
  int nn = n0;
  for (; nn + 8 <= n1; nn += 8) {
    float a0 = __half2float(h[(size_t)(nn + 0) * HID + lane]);
    float a1 = __half2float(h[(size_t)(nn + 1) * HID + lane]);
    float a2 = __half2float(h[(size_t)(nn + 2) * HID + lane]);
    float a3 = __half2float(h[(size_t)(nn + 3) * HID + lane]);
    float a4 = __half2float(h[(size_t)(nn + 4) * HID + lane]);
    float a5 = __half2float(h[(size_t)(nn + 5) * HID + lane]);
    float a6 = __half2float(h[(size_t)(nn + 6) * HID + lane]);
    float a7 = __half2float(h[(size_t)(nn + 7) * HID + lane]);
    acc += a0 + a1 + a2 + a3;
    acc2 += a4 + a5 + a6 + a7;
  }
  for (; nn < n1; ++nn) acc += __half2float(h[(size_t)nn * HID + lane]);
  acc += acc2;
  float s = acc / fmaxf((float)(n1 - n0), 1.0f);
#pragma unroll
  for (int o = 0; o < NUM_CLASSES; ++o) {
    float p = s * Wfc[lane * NUM_CLASSES + o];
#pragma unroll
    for (int m = 32; m >= 1; m >>= 1) p += __shfl_xor(p, m);
    if (lane == o) out[(size_t)g * NUM_CLASSES + o] = p + bfc[o];
  }
}

// ---------------- launch -----------------------------------------------------
extern "C" void kernel_launch(void* const* d_in, const int* in_sizes, int n_in,
                              void* d_out, int out_size, void* d_ws, size_t ws_size,
                              hipStream_t stream) {
  const float* x = (const float*)d_in[0];
  const int* edge_index = (const int*)d_in[1];
  const int* batch = (const int*)d_in[2];
  const float* W1 = (const float*)d_in[3];
  const float* b1 = (const float*)d_in[4];
  const float* W2 = (const float*)d_in[5];
  const float* b2 = (const float*)d_in[6];
  const float* W3 = (const float*)d_in[7];
  const float* b3 = (const float*)d_in[8];
  const float* Wfc = (const float*)d_in[9];
  const float* bfc = (const float*)d_in[10];
  float* out = (float*)d_out;

  const int* src = edge_index;
  const int* dst = edge_index + N_EDGES;

  // workspace layout
  char* w = (char*)d_ws;
  __half* h16 = (__half*)w;                        // N*64 f16 (aggregate out / GEMM A)
  __half* hp = h16 + (size_t)N_NODES * HID;        // N*64 f16 (GEMM out, gather buf)
  float* dinv = (float*)(hp + (size_t)N_NODES * HID);  // N
  int* row_ptr = (int*)(dinv + N_NODES);           // N+1
  int* csr_src = row_ptr + (N_NODES + 1);          // E
  int* bucket_base = csr_src + N_EDGES;            // NBUCKET+1
  int* bucket_cursor = bucket_base + NBUCKET + 1;  // NBUCKET
  int* blk_hist = bucket_cursor + NBUCKET;         // NHBLK*NBUCKET
  unsigned* pair_buf = (unsigned*)h16;  // alias: dead before aggregate1 writes h16

  // CSR build (no memsets needed: blk_hist fully written before read)
  bucket_hist_kernel<<<NHBLK, 256, 0, stream>>>(dst, blk_hist);
  bucket_scan_kernel<<<1, 256, 0, stream>>>(blk_hist, bucket_base, bucket_cursor,
                                            row_ptr);
  pair_scatter_kernel<<<NHBLK, 256, 0, stream>>>(src, dst, bucket_cursor, blk_hist,
                                                 pair_buf);
  bucket_fill_kernel<<<NBUCKET, 256, 0, stream>>>(pair_buf, bucket_base, csr_src,
                                                  row_ptr, dinv);

  const int ggrid = (N_NODES + 127) / 128;
  const int agrid = (N_NODES + 7) / 8;

  // layer 1
  mfma_gemm_kernel<IN_DIM, true><<<ggrid, 256, 0, stream>>>(x, W1, dinv, (f16*)hp,
                                                            N_NODES);
  aggregate_kernel<<<agrid, 256, 0, stream>>>(hp, row_ptr, csr_src, dinv, b1, h16, 1);
  // layer 2
  mfma_gemm_kernel<HID, false><<<ggrid, 256, 0, stream>>>(h16, W2, dinv, (f16*)hp,
                                                          N_NODES);
  aggregate_kernel<<<agrid, 256, 0, stream>>>(hp, row_ptr, csr_src, dinv, b2, h16, 1);
  // layer 3
  mfma_gemm_kernel<HID, false><<<ggrid, 256, 0, stream>>>(h16, W3, dinv, (f16*)hp,
                                                          N_NODES);
  aggregate_kernel<<<agrid, 256, 0, stream>>>(hp, row_ptr, csr_src, dinv, b3, h16, 0);

  // fused pool + fc
  pool_fc_kernel<<<(NUM_GRAPHS + 3) / 4, 256, 0, stream>>>(h16, batch, Wfc, bfc, out);
}

// Round 11
// 287.895 us; speedup vs baseline: 1.2683x; 1.0778x over previous
//
#include <hip/hip_runtime.h>
#include <hip/hip_fp16.h>

#define N_NODES 100000
#define N_EDGES 3200000
#define IN_DIM 128
#define HID 64
#define NUM_GRAPHS 512
#define NUM_CLASSES 10

#define BSHIFT 9
#define BUCKET_W 512
#define NBUCKET ((N_NODES + BUCKET_W - 1) / BUCKET_W)  // 196
#define SRC_BITS 17
#define SRC_MASK ((1 << SRC_BITS) - 1)
#define NHBLK 256  // blocks in hist/scatter

typedef _Float16 f16;
typedef f16 f16x8 __attribute__((ext_vector_type(8)));
typedef float f32x4 __attribute__((ext_vector_type(4)));

// ---------------- CSR build (bucketed, no per-edge global atomics) ----------

__global__ __launch_bounds__(256) void bucket_hist_kernel(const int* __restrict__ dst,
                                                          int* __restrict__ blk_hist) {
  __shared__ int h[NBUCKET];
  for (int i = threadIdx.x; i < NBUCKET; i += 256) h[i] = 0;
  __syncthreads();
  const int4* d4 = (const int4*)dst;
  const int nv = N_EDGES / 4 / NHBLK;  // 3125 vectors per block
  int v0 = blockIdx.x * nv, v1 = v0 + nv;
  for (int v = v0 + threadIdx.x; v < v1; v += 256) {
    int4 d = d4[v];
    atomicAdd(&h[d.x >> BSHIFT], 1);
    atomicAdd(&h[d.y >> BSHIFT], 1);
    atomicAdd(&h[d.z >> BSHIFT], 1);
    atomicAdd(&h[d.w >> BSHIFT], 1);
  }
  __syncthreads();
  for (int i = threadIdx.x; i < NBUCKET; i += 256)
    blk_hist[blockIdx.x * NBUCKET + i] = h[i];
}

__global__ __launch_bounds__(256) void bucket_scan_kernel(const int* __restrict__ blk_hist,
                                                          int* __restrict__ bucket_base,
                                                          int* __restrict__ bucket_cursor,
                                                          int* __restrict__ row_ptr) {
  __shared__ int cnt[NBUCKET];
  int t = threadIdx.x;
  if (t < NBUCKET) {
    int s = 0;
    for (int b = 0; b < NHBLK; ++b) s += blk_hist[b * NBUCKET + t];
    cnt[t] = s;
  }
  __syncthreads();
  if (t < 64) {
    int carry = 0;
    for (int base = 0; base < NBUCKET; base += 64) {
      int i = base + t;
      int v = (i < NBUCKET) ? cnt[i] : 0;
      int x = v;
#pragma unroll
      for (int off = 1; off < 64; off <<= 1) {
        int tt = __shfl_up(x, off);
        if (t >= off) x += tt;
      }
      if (i < NBUCKET) {
        int ex = carry + x - v;
        bucket_base[i] = ex;
        bucket_cursor[i] = ex;
      }
      carry += __shfl(x, 63);
    }
    if (t == 0) {
      bucket_base[NBUCKET] = carry;
      row_ptr[N_NODES] = carry;  // == N_EDGES
    }
  }
}

__global__ __launch_bounds__(256) void pair_scatter_kernel(const int* __restrict__ src,
                                                           const int* __restrict__ dst,
                                                           int* __restrict__ bucket_cursor,
                                                           const int* __restrict__ blk_hist,
                                                           unsigned* __restrict__ pair_buf) {
  __shared__ int h[NBUCKET];
  for (int i = threadIdx.x; i < NBUCKET; i += 256) {
    int c = blk_hist[blockIdx.x * NBUCKET + i];
    h[i] = c ? atomicAdd(&bucket_cursor[i], c) : 0;
  }
  __syncthreads();
  const int4* d4 = (const int4*)dst;
  const int4* s4 = (const int4*)src;
  const int nv = N_EDGES / 4 / NHBLK;  // 3125
  int v0 = blockIdx.x * nv, v1 = v0 + nv;
  for (int v = v0 + threadIdx.x; v < v1; v += 256) {
    int4 d = d4[v];
    int4 s = s4[v];
    int p0 = atomicAdd(&h[d.x >> BSHIFT], 1);
    pair_buf[p0] = ((unsigned)(d.x & (BUCKET_W - 1)) << SRC_BITS) | (unsigned)s.x;
    int p1 = atomicAdd(&h[d.y >> BSHIFT], 1);
    pair_buf[p1] = ((unsigned)(d.y & (BUCKET_W - 1)) << SRC_BITS) | (unsigned)s.y;
    int p2 = atomicAdd(&h[d.z >> BSHIFT], 1);
    pair_buf[p2] = ((unsigned)(d.z & (BUCKET_W - 1)) << SRC_BITS) | (unsigned)s.z;
    int p3 = atomicAdd(&h[d.w >> BSHIFT], 1);
    pair_buf[p3] = ((unsigned)(d.w & (BUCKET_W - 1)) << SRC_BITS) | (unsigned)s.w;
  }
}

// 512 threads, uint4-vectorized pair reads in both passes.
__global__ __launch_bounds__(512) void bucket_fill_kernel(const unsigned* __restrict__ pair_buf,
                                                          const int* __restrict__ bucket_base,
                                                          int* __restrict__ csr_src,
                                                          int* __restrict__ row_ptr,
                                                          float* __restrict__ dinv) {
  int b = blockIdx.x;
  int n0 = b << BSHIFT;
  int nn = min(BUCKET_W, N_NODES - n0);
  int eb0 = bucket_base[b], eb1 = bucket_base[b + 1];
  __shared__ int hist[BUCKET_W];
  __shared__ int wsum[8];
  int tid = threadIdx.x;
  hist[tid] = 0;
  __syncthreads();
  int a0 = (eb0 + 3) & ~3;           // first aligned
  int a1 = eb1 & ~3;                 // end aligned
  if (a0 > eb1) a0 = eb1;
  // pass 1: histogram
  for (int e = eb0 + tid; e < min(a0, eb1); e += 512)
    atomicAdd(&hist[pair_buf[e] >> SRC_BITS], 1);
  for (int e4 = (a0 >> 2) + tid; e4 < (a1 >> 2); e4 += 512) {
    uint4 p = ((const uint4*)pair_buf)[e4];
    atomicAdd(&hist[p.x >> SRC_BITS], 1);
    atomicAdd(&hist[p.y >> SRC_BITS], 1);
    atomicAdd(&hist[p.z >> SRC_BITS], 1);
    atomicAdd(&hist[p.w >> SRC_BITS], 1);
  }
  for (int e = max(a1, a0) + tid; e < eb1; e += 512)
    atomicAdd(&hist[pair_buf[e] >> SRC_BITS], 1);
  __syncthreads();
  // scan 512 bins, thread t owns bin t (8 waves)
  int v = hist[tid];
  int lane = tid & 63, wid = tid >> 6;
  int x = v;
#pragma unroll
  for (int off = 1; off < 64; off <<= 1) {
    int t = __shfl_up(x, off);
    if (lane >= off) x += t;
  }
  if (lane == 63) wsum[wid] = x;
  __syncthreads();
  if (tid == 0) {
    int c = 0;
#pragma unroll
    for (int i = 0; i < 8; ++i) {
      int t = wsum[i];
      wsum[i] = c;
      c += t;
    }
  }
  __syncthreads();
  int base = eb0 + x - v + wsum[wid];  // exclusive
  if (tid < nn) {
    row_ptr[n0 + tid] = base;
    dinv[n0 + tid] = rsqrtf((float)(v + 1));
  }
  __syncthreads();
  hist[tid] = base;  // cursor
  __syncthreads();
  // pass 2: fill
  for (int e = eb0 + tid; e < min(a0, eb1); e += 512) {
    unsigned p = pair_buf[e];
    csr_src[atomicAdd(&hist[p >> SRC_BITS], 1)] = (int)(p & SRC_MASK);
  }
  for (int e4 = (a0 >> 2) + tid; e4 < (a1 >> 2); e4 += 512) {
    uint4 p = ((const uint4*)pair_buf)[e4];
    csr_src[atomicAdd(&hist[p.x >> SRC_BITS], 1)] = (int)(p.x & SRC_MASK);
    csr_src[atomicAdd(&hist[p.y >> SRC_BITS], 1)] = (int)(p.y & SRC_MASK);
    csr_src[atomicAdd(&hist[p.z >> SRC_BITS], 1)] = (int)(p.z & SRC_MASK);
    csr_src[atomicAdd(&hist[p.w >> SRC_BITS], 1)] = (int)(p.w & SRC_MASK);
  }
  for (int e = max(a1, a0) + tid; e < eb1; e += 512) {
    unsigned p = pair_buf[e];
    csr_src[atomicAdd(&hist[p >> SRC_BITS], 1)] = (int)(p & SRC_MASK);
  }
}

// ---------------- MFMA GEMM: hp[n][64] = f16((A[n][K]@W[K][64])*dinv[n]) ----
template <int K, bool SRC_F32>
__global__ __launch_bounds__(256) void mfma_gemm_kernel(const void* __restrict__ Asrc,
                                                        const float* __restrict__ W,
                                                        const float* __restrict__ dinv,
                                                        f16* __restrict__ hp, int n) {
  __shared__ f16 Ah[128][K + 8];
  __shared__ f16 Wt[64][K + 8];  // Wt[c][k] = W[k][c]
  int tid = threadIdx.x;
  int row0 = blockIdx.x * 128;
  for (int idx = tid; idx < K * 64; idx += 256) {
    int k = idx >> 6, c = idx & 63;
    Wt[c][k] = (f16)W[idx];
  }
  if (SRC_F32) {
    const float* A = (const float*)Asrc;
    for (int idx = tid * 4; idx < 128 * K; idx += 1024) {
      int r = idx / K, c = idx % K;
      float4 v = make_float4(0.f, 0.f, 0.f, 0.f);
      if (row0 + r < n) v = *(const float4*)&A[(size_t)(row0 + r) * K + c];
      Ah[r][c] = (f16)v.x;
      Ah[r][c + 1] = (f16)v.y;
      Ah[r][c + 2] = (f16)v.z;
      Ah[r][c + 3] = (f16)v.w;
    }
  } else {
    const f16* A = (const f16*)Asrc;
    for (int idx = tid * 8; idx < 128 * K; idx += 2048) {
      int r = idx / K, c = idx % K;
      uint4 z = make_uint4(0u, 0u, 0u, 0u);
      if (row0 + r < n) z = *(const uint4*)&A[(size_t)(row0 + r) * K + c];
      *(uint4*)&Ah[r][c] = z;
    }
  }
  __syncthreads();
  int w = tid >> 6, lane = tid & 63;
  int m0 = 32 * w;
  int kbase = (lane >> 4) * 8;
  int la = lane & 15;
  f32x4 acc[2][4] = {};
#pragma unroll
  for (int ks = 0; ks < K / 32; ++ks) {
    f16x8 a0 = *(const f16x8*)&Ah[m0 + la][32 * ks + kbase];
    f16x8 a1 = *(const f16x8*)&Ah[m0 + 16 + la][32 * ks + kbase];
#pragma unroll
    for (int t = 0; t < 4; ++t) {
      f16x8 b = *(const f16x8*)&Wt[16 * t + la][32 * ks + kbase];
      acc[0][t] = __builtin_amdgcn_mfma_f32_16x16x32_f16(a0, b, acc[0][t], 0, 0, 0);
      acc[1][t] = __builtin_amdgcn_mfma_f32_16x16x32_f16(a1, b, acc[1][t], 0, 0, 0);
    }
  }
#pragma unroll
  for (int mt = 0; mt < 2; ++mt) {
#pragma unroll
    for (int j = 0; j < 4; ++j) {
      int grow = row0 + m0 + 16 * mt + (lane >> 4) * 4 + j;
      if (grow < n) {
        float di = dinv[grow];
#pragma unroll
        for (int t = 0; t < 4; ++t)
          hp[(size_t)grow * 64 + 16 * t + la] = (f16)(acc[mt][t][j] * di);
      }
    }
  }
}

// ---------------- Aggregate: 2 nodes per wave, half-wave per node -----------
// Main loop: 16-deep gather tiers. Tail: ONE masked 16-deep round with
// indices clamped to end-1 (duplicate addresses -> L1-hot, ~free).
#define GATH2(H)                                                     \
  {                                                                  \
    int s_[H];                                                       \
    _Pragma("unroll") for (int i_ = 0; i_ < H; ++i_)                 \
        s_[i_] = csr_src[e + i_];                                    \
    float2 v_[H];                                                    \
    _Pragma("unroll") for (int i_ = 0; i_ < H; ++i_)                 \
        v_[i_] = __half22float2(hp2[(unsigned)(s_[i_] * 32 + l)]);   \
    _Pragma("unroll") for (int i_ = 0; i_ < H; ++i_) {               \
      acc.x += v_[i_].x;                                             \
      acc.y += v_[i_].y;                                             \
    }                                                                \
  }

__global__ __launch_bounds__(256) void aggregate_kernel(
    const __half* __restrict__ hp, const int* __restrict__ row_ptr,
    const int* __restrict__ csr_src, const float* __restrict__ dinv,
    const float* __restrict__ bias, __half* __restrict__ out, int relu) {
  int node = blockIdx.x * 8 + (threadIdx.x >> 5);
  if (node >= N_NODES) return;
  int l = threadIdx.x & 31;  // dim-pair index
  const __half2* hp2 = (const __half2*)hp;
  int beg = row_ptr[node], end = row_ptr[node + 1];
  float2 acc = __half22float2(hp2[(unsigned)(node * 32 + l)]);  // self loop
  int e = beg;
  int rem = end - beg;
  while (rem >= 16) {
    GATH2(16);
    e += 16;
    rem -= 16;
  }
  if (rem) {  // masked 16-round; clamped dup indices are L1-hot
    int last = end - 1;
    int s_[16];
#pragma unroll
    for (int i = 0; i < 16; ++i) s_[i] = csr_src[min(e + i, last)];
    float2 v_[16];
#pragma unroll
    for (int i = 0; i < 16; ++i)
      v_[i] = __half22float2(hp2[(unsigned)(s_[i] * 32 + l)]);
#pragma unroll
    for (int i = 0; i < 16; ++i) {
      if (i < rem) {
        acc.x += v_[i].x;
        acc.y += v_[i].y;
      }
    }
  }
  float di = dinv[node];
  float2 b = *(const float2*)&bias[2 * l];
  float rx = acc.x * di + b.x;
  float ry = acc.y * di + b.y;
  if (relu) {
    rx = fmaxf(rx, 0.0f);
    ry = fmaxf(ry, 0.0f);
  }
  ((__half2*)out)[(unsigned)(node * 32 + l)] = __floats2half2_rn(rx, ry);
}

// ---------------- Fused mean-pool + FC (wave per graph, no atomics) ---------
__global__ __launch_bounds__(256) void pool_fc_kernel(const __half* __restrict__ h,
                                                      const int* __restrict__ batch,
                                                      const float* __restrict__ Wfc,
                                                      const float* __restrict__ bfc,
                                                      float* __restrict__ out) {
  int g = blockIdx.x * 4 + (threadIdx.x >> 6);
  if (g >= NUM_GRAPHS) return;
  int lane = threadIdx.x & 63;
  int lo = 0, hi = N_NODES;
  while (lo < hi) {
    int m = (lo + hi) >> 1;
    if (batch[m] < g) lo = m + 1; else hi = m;
  }
  int n0 = lo;
  hi = N_NODES;
  while (lo < hi) {
    int m = (lo + hi) >> 1;
    if (batch[m] < g + 1) lo = m + 1; else hi = m;
  }
  int n1 = lo;
  float acc = 0.f, acc2 = 0.f;
  int nn = n0;
  for (; nn + 8 <= n1; nn += 8) {
    float a0 = __half2float(h[(size_t)(nn + 0) * HID + lane]);
    float a1 = __half2float(h[(size_t)(nn + 1) * HID + lane]);
    float a2 = __half2float(h[(size_t)(nn + 2) * HID + lane]);
    float a3 = __half2float(h[(size_t)(nn + 3) * HID + lane]);
    float a4 = __half2float(h[(size_t)(nn + 4) * HID + lane]);
    float a5 = __half2float(h[(size_t)(nn + 5) * HID + lane]);
    float a6 = __half2float(h[(size_t)(nn + 6) * HID + lane]);
    float a7 = __half2float(h[(size_t)(nn + 7) * HID + lane]);
    acc += a0 + a1 + a2 + a3;
    acc2 += a4 + a5 + a6 + a7;
  }
  for (; nn < n1; ++nn) acc += __half2float(h[(size_t)nn * HID + lane]);
  acc += acc2;
  float s = acc / fmaxf((float)(n1 - n0), 1.0f);
#pragma unroll
  for (int o = 0; o < NUM_CLASSES; ++o) {
    float p = s * Wfc[lane * NUM_CLASSES + o];
#pragma unroll
    for (int m = 32; m >= 1; m >>= 1) p += __shfl_xor(p, m);
    if (lane == o) out[(size_t)g * NUM_CLASSES + o] = p + bfc[o];
  }
}

// ---------------- launch -----------------------------------------------------
extern "C" void kernel_launch(void* const* d_in, const int* in_sizes, int n_in,
                              void* d_out, int out_size, void* d_ws, size_t ws_size,
                              hipStream_t stream) {
  const float* x = (const float*)d_in[0];
  const int* edge_index = (const int*)d_in[1];
  const int* batch = (const int*)d_in[2];
  const float* W1 = (const float*)d_in[3];
  const float* b1 = (const float*)d_in[4];
  const float* W2 = (const float*)d_in[5];
  const float* b2 = (const float*)d_in[6];
  const float* W3 = (const float*)d_in[7];
  const float* b3 = (const float*)d_in[8];
  const float* Wfc = (const float*)d_in[9];
  const float* bfc = (const float*)d_in[10];
  float* out = (float*)d_out;

  const int* src = edge_index;
  const int* dst = edge_index + N_EDGES;

  // workspace layout
  char* w = (char*)d_ws;
  __half* h16 = (__half*)w;                        // N*64 f16 (aggregate out / GEMM A)
  __half* hp = h16 + (size_t)N_NODES * HID;        // N*64 f16 (GEMM out, gather buf)
  float* dinv = (float*)(hp + (size_t)N_NODES * HID);  // N
  int* row_ptr = (int*)(dinv + N_NODES);           // N+1
  int* csr_src = row_ptr + (N_NODES + 1);          // E
  int* bucket_base = csr_src + N_EDGES;            // NBUCKET+1
  int* bucket_cursor = bucket_base + NBUCKET + 1;  // NBUCKET
  int* blk_hist = bucket_cursor + NBUCKET;         // NHBLK*NBUCKET
  unsigned* pair_buf = (unsigned*)h16;  // alias: dead before aggregate1 writes h16

  // CSR build (no memsets: blk_hist fully written before read)
  bucket_hist_kernel<<<NHBLK, 256, 0, stream>>>(dst, blk_hist);
  bucket_scan_kernel<<<1, 256, 0, stream>>>(blk_hist, bucket_base, bucket_cursor,
                                            row_ptr);
  pair_scatter_kernel<<<NHBLK, 256, 0, stream>>>(src, dst, bucket_cursor, blk_hist,
                                                 pair_buf);
  bucket_fill_kernel<<<NBUCKET, 512, 0, stream>>>(pair_buf, bucket_base, csr_src,
                                                  row_ptr, dinv);

  const int ggrid = (N_NODES + 127) / 128;
  const int agrid = (N_NODES + 7) / 8;

  // layer 1
  mfma_gemm_kernel<IN_DIM, true><<<ggrid, 256, 0, stream>>>(x, W1, dinv, (f16*)hp,
                                                            N_NODES);
  aggregate_kernel<<<agrid, 256, 0, stream>>>(hp, row_ptr, csr_src, dinv, b1, h16, 1);
  // layer 2
  mfma_gemm_kernel<HID, false><<<ggrid, 256, 0, stream>>>(h16, W2, dinv, (f16*)hp,
                                                          N_NODES);
  aggregate_kernel<<<agrid, 256, 0, stream>>>(hp, row_ptr, csr_src, dinv, b2, h16, 1);
  // layer 3
  mfma_gemm_kernel<HID, false><<<ggrid, 256, 0, stream>>>(h16, W3, dinv, (f16*)hp,
                                                          N_NODES);
  aggregate_kernel<<<agrid, 256, 0, stream>>>(hp, row_ptr, csr_src, dinv, b3, h16, 0);

  // fused pool + fc
  pool_fc_kernel<<<(NUM_GRAPHS + 3) / 4, 256, 0, stream>>>(h16, batch, Wfc, bfc, out);
}